// Round 6
// baseline (362.502 us; speedup 1.0000x reference)
//
#include <hip/hip_runtime.h>
#include <hip/hip_bf16.h>
#include <stdint.h>

typedef short bf16x8 __attribute__((ext_vector_type(8)));
typedef float f32x4 __attribute__((ext_vector_type(4)));

#define DEVI static __device__ __forceinline__

DEVI ushort f2bf(float f) {
  union { float f; uint32_t u; } v; v.f = f;
  uint32_t u = v.u;
  return (ushort)((u + 0x7fffu + ((u >> 16) & 1u)) >> 16);
}

DEVI void gload16(const void* g, void* l) {
  __builtin_amdgcn_global_load_lds((const __attribute__((address_space(1))) void*)g,
                                   (__attribute__((address_space(3))) void*)l,
                                   16, 0, 0);
}

#define SB() __builtin_amdgcn_sched_barrier(0)
#define BAR() __builtin_amdgcn_s_barrier()
#define LGK0() { asm volatile("s_waitcnt lgkmcnt(0)" ::: "memory"); SB(); }
#define VM0()  { asm volatile("s_waitcnt vmcnt(0)" ::: "memory"); SB(); }
#define MFMA(a, b, c) __builtin_amdgcn_mfma_f32_16x16x32_bf16((a), (b), (c), 0, 0, 0)

// ---------------- weight fold / convert ----------------

__global__ void fold_kernel(const float* __restrict__ W, const float* __restrict__ up,
                            const float* __restrict__ down, ushort* __restrict__ out,
                            int OUT, int IN, int transpose, float scale) {
  int idx = blockIdx.x * 256 + threadIdx.x;
  if (idx >= OUT * IN) return;
  int o = idx / IN, i = idx % IN;
  float v = W[idx];
#pragma unroll
  for (int r = 0; r < 4; ++r) v += up[o * 4 + r] * down[r * IN + i];
  v *= scale;
  out[transpose ? ((long)i * OUT + o) : idx] = f2bf(v);
}

__global__ void cvt_kernel(const float* __restrict__ in, ushort* __restrict__ out, int n8) {
  int idx = blockIdx.x * 256 + threadIdx.x;
  if (idx >= n8) return;
  const float4* p = (const float4*)(in + (long)idx * 8);
  float4 a = p[0], b = p[1];
  union { ushort us[8]; uint4 v; } r;
  r.us[0] = f2bf(a.x); r.us[1] = f2bf(a.y); r.us[2] = f2bf(a.z); r.us[3] = f2bf(a.w);
  r.us[4] = f2bf(b.x); r.us[5] = f2bf(b.y); r.us[6] = f2bf(b.z); r.us[7] = f2bf(b.w);
  *(uint4*)(out + (long)idx * 8) = r.v;
}

// ---------------- small-GEMM kernel (128x128, BK=32) — proven ----------------

__global__ __launch_bounds__(256) void gemm_bt(
    const ushort* __restrict__ A, long sA0, long sA1, int lda, int validM,
    const ushort* __restrict__ B, long sB0, long sB1, int ldb, int validN,
    float* __restrict__ C32, ushort* __restrict__ C16, long sC0, long sC1, int ldc,
    const float* __restrict__ bias, int K)
{
  __shared__ ushort As[128 * 32];
  __shared__ ushort Bs[128 * 32];

  const int z = blockIdx.z;
  const ushort* Ab = A + (long)(z >> 3) * sA0 + (long)(z & 7) * sA1;
  const ushort* Bb = B + (long)(z >> 3) * sB0 + (long)(z & 7) * sB1;
  const int m0 = blockIdx.x * 128;
  const int n0 = blockIdx.y * 128;
  const int tid = threadIdx.x;
  const int lane = tid & 63;
  const int wid = tid >> 6;

  const int c0 = tid;
  const int arow0 = min(m0 + (c0 >> 2), validM - 1);
  const int arow1 = min(m0 + (c0 >> 2) + 64, validM - 1);
  const int brow0 = min(n0 + (c0 >> 2), validN - 1);
  const int brow1 = min(n0 + (c0 >> 2) + 64, validN - 1);
  const int seg = (c0 & 3) * 8;

  const int wr = (wid >> 1) * 64;
  const int wc = (wid & 1) * 64;
  const int frow = lane & 15;
  const int fk = (lane >> 4) * 8;

  f32x4 acc[4][4] = {};

  for (int kt = 0; kt < K; kt += 32) {
    gload16(Ab + (long)arow0 * lda + kt + seg, As + c0 * 8);
    gload16(Ab + (long)arow1 * lda + kt + seg, As + (c0 + 256) * 8);
    gload16(Bb + (long)brow0 * ldb + kt + seg, Bs + c0 * 8);
    gload16(Bb + (long)brow1 * ldb + kt + seg, Bs + (c0 + 256) * 8);
    __syncthreads();

    bf16x8 af[4], bfr[4];
#pragma unroll
    for (int m = 0; m < 4; ++m)
      af[m] = *(const bf16x8*)(As + (wr + m * 16 + frow) * 32 + fk);
#pragma unroll
    for (int n = 0; n < 4; ++n)
      bfr[n] = *(const bf16x8*)(Bs + (wc + n * 16 + frow) * 32 + fk);
#pragma unroll
    for (int m = 0; m < 4; ++m)
#pragma unroll
      for (int n = 0; n < 4; ++n)
        acc[m][n] = MFMA(af[m], bfr[n], acc[m][n]);
    __syncthreads();
  }

  const long cb = (long)(z >> 3) * sC0 + (long)(z & 7) * sC1;
  const int crow = m0 + wr + (lane >> 4) * 4;
  const int ccol = n0 + wc + (lane & 15);
#pragma unroll
  for (int m = 0; m < 4; ++m)
#pragma unroll
    for (int n = 0; n < 4; ++n)
#pragma unroll
      for (int j = 0; j < 4; ++j) {
        int r = crow + m * 16 + j;
        int c = ccol + n * 16;
        if (r < validM && c < validN) {
          float v = acc[m][n][j];
          if (bias) v += bias[c];
          if (C32) C32[cb + (long)r * ldc + c] = v;
          else     C16[cb + (long)r * ldc + c] = f2bf(v);
        }
      }
}

// ---------------- fused scores GEMM + softmax (8-phase class schedule) ----------------
// Tile 256 rows x 192 cols (2 heads x 96), z=batch. K=1280 = 20 steps of 64.
// Waves 4M x 2N: wave = 64 rows x 96 cols = one full head -> wave-local softmax.
// LDS per buf: A[256][64] (16384 us) | B[192][64] (12288 us); 2 bufs = 57344 us.
// 8-slot XOR swizzle key = row&7 (r2-verified 0-conflict). A reg-staged from f32
// (issue p0, cvt+ds_write p3); B gload_lds (linear dest, pre-swizzled source).
__global__ __launch_bounds__(512, 1) void score_softmax(
    const float* __restrict__ hs, const ushort* __restrict__ Mt,
    ushort* __restrict__ probs)
{
  __shared__ ushort lds[57344];

  const int z = blockIdx.z;
  const int s0 = blockIdx.x * 256;
  const int h0 = blockIdx.y * 2;
  const int tid = threadIdx.x;
  const int lane = tid & 63;
  const int wid = tid >> 6;
  const int wM = wid >> 1;                  // 0..3
  const int wN = wid & 1;                   // 0..1
  const int l15 = lane & 15;
  const int l4 = lane >> 4;

  // A reg-staging: thread -> (row ar, half ah) covering 32 f32 K-elems
  const int ar = tid >> 1, ah = tid & 1;
  const float* ag = hs + ((long)z * 4096 + s0 + ar) * 1280 + ah * 32;
  const int akey = ar & 7;
  int awoff[4];
#pragma unroll
  for (int i = 0; i < 4; ++i) awoff[i] = ar * 64 + (((ah * 4 + i) ^ akey) * 8);

  // B gload staging: 3 instrs, instr j covers rows j*64..j*64+63
  const ushort* MtB = Mt + (long)z * (640L * 1280);
  const int rb0 = tid >> 3, sl = tid & 7;
  long bsrc[3]; int bdst[3];
#pragma unroll
  for (int j = 0; j < 3; ++j) {
    int rb = j * 64 + rb0;
    int c = h0 * 96 + rb;
    int hh = c / 96, tt = c - hh * 96;
    tt = min(tt, 76);
    bsrc[j] = (long)(hh * 77 + tt) * 1280 + ((sl ^ (rb & 7)) * 8);
    bdst[j] = 16384 + j * 4096 + tid * 8;
  }

  // fragment offsets
  int aoff[2][4], boff[2][6];
#pragma unroll
  for (int kk = 0; kk < 2; ++kk) {
#pragma unroll
    for (int m = 0; m < 4; ++m) {
      int r = wM * 64 + m * 16 + l15;
      aoff[kk][m] = r * 64 + (((kk * 4 + l4) ^ (r & 7)) * 8);
    }
#pragma unroll
    for (int n = 0; n < 6; ++n) {
      int r = wN * 96 + n * 16 + l15;
      boff[kk][n] = 16384 + r * 64 + (((kk * 4 + l4) ^ (r & 7)) * 8);
    }
  }

  f32x4 acc[4][6] = {};
  float4 af[8];

#define SS_GLB(nb, kt) { \
    gload16(MtB + bsrc[0] + (kt), &lds[(nb) + bdst[0]]); \
    gload16(MtB + bsrc[1] + (kt), &lds[(nb) + bdst[1]]); \
    gload16(MtB + bsrc[2] + (kt), &lds[(nb) + bdst[2]]); }
#define SS_LOADA(kt) { _Pragma("unroll") \
    for (int i = 0; i < 8; ++i) af[i] = *(const float4*)(ag + (kt) + i * 4); }
#define SS_CVTW(nb) { \
    union { ushort us[8]; bf16x8 v; } cw; \
    _Pragma("unroll") \
    for (int i = 0; i < 4; ++i) { \
      float4 x = af[2 * i], y = af[2 * i + 1]; \
      cw.us[0] = f2bf(x.x); cw.us[1] = f2bf(x.y); cw.us[2] = f2bf(x.z); cw.us[3] = f2bf(x.w); \
      cw.us[4] = f2bf(y.x); cw.us[5] = f2bf(y.y); cw.us[6] = f2bf(y.z); cw.us[7] = f2bf(y.w); \
      *(bf16x8*)(&lds[(nb) + awoff[i]]) = cw.v; \
    } }
#define SS_MF(MLO, KK, A0, A1) { \
    __builtin_amdgcn_s_setprio(1); \
    _Pragma("unroll") \
    for (int n = 0; n < 6; ++n) { \
      acc[MLO][n] = MFMA(A0, bfv[n], acc[MLO][n]); \
      acc[MLO + 1][n] = MFMA(A1, bfv[n], acc[MLO + 1][n]); \
    } \
    __builtin_amdgcn_s_setprio(0); }

  // prologue: stage step 0 into buf 0
  SS_GLB(0, 0)
  SS_LOADA(0)
  SS_CVTW(0)
  VM0()
  LGK0()
  BAR(); SB();

  for (int s = 0; s < 20; ++s) {
    const int cb = (s & 1) * 28672;
    const int nb = 28672 - cb;
    const int kt1 = (s + 1) * 64;
    const bool pre = (s + 1 < 20);
    bf16x8 a0, a1, bfv[6];

    // ---- p0: frags (m0,m1 + B k0), stage next (B gload + A reg-issue)
    a0 = *(const bf16x8*)(&lds[cb + aoff[0][0]]);
    a1 = *(const bf16x8*)(&lds[cb + aoff[0][1]]);
#pragma unroll
    for (int n = 0; n < 6; ++n) bfv[n] = *(const bf16x8*)(&lds[cb + boff[0][n]]);
    if (pre) { SS_GLB(nb, kt1) SS_LOADA(kt1) }
    SB(); BAR();
    LGK0()
    SS_MF(0, 0, a0, a1)
    SB(); BAR();

    // ---- p1: frags (m2,m3 k0)
    a0 = *(const bf16x8*)(&lds[cb + aoff[0][2]]);
    a1 = *(const bf16x8*)(&lds[cb + aoff[0][3]]);
    SB(); BAR();
    LGK0()
    SS_MF(2, 0, a0, a1)
    SB(); BAR();

    // ---- p2: frags (m0,m1 + B k1)
    a0 = *(const bf16x8*)(&lds[cb + aoff[1][0]]);
    a1 = *(const bf16x8*)(&lds[cb + aoff[1][1]]);
#pragma unroll
    for (int n = 0; n < 6; ++n) bfv[n] = *(const bf16x8*)(&lds[cb + boff[1][n]]);
    SB(); BAR();
    LGK0()
    SS_MF(0, 1, a0, a1)
    SB(); BAR();

    // ---- p3: frags (m2,m3 k1), cvt+write A(s+1), drain stage
    a0 = *(const bf16x8*)(&lds[cb + aoff[1][2]]);
    a1 = *(const bf16x8*)(&lds[cb + aoff[1][3]]);
    if (pre) { SS_CVTW(nb) }
    VM0()
    SB(); BAR();
    LGK0()
    SS_MF(2, 1, a0, a1)
    SB(); BAR();
  }

  // ---- softmax over 77 valid cols per head (wave-local)
#pragma unroll
  for (int m = 0; m < 4; ++m)
#pragma unroll
    for (int j = 0; j < 4; ++j) {
      float mx = -1e30f;
#pragma unroll
      for (int n = 0; n < 6; ++n)
        if (n * 16 + l15 < 77) mx = fmaxf(mx, acc[m][n][j]);
#pragma unroll
      for (int o = 8; o; o >>= 1) mx = fmaxf(mx, __shfl_xor(mx, o));
      float sum = 0.f;
#pragma unroll
      for (int n = 0; n < 6; ++n) {
        float e = (n * 16 + l15 < 77) ? __expf(acc[m][n][j] - mx) : 0.f;
        acc[m][n][j] = e;
        sum += e;
      }
#pragma unroll
      for (int o = 8; o; o >>= 1) sum += __shfl_xor(sum, o);
      float inv = 1.f / sum;
#pragma unroll
      for (int n = 0; n < 6; ++n) acc[m][n][j] *= inv;
    }

  // ---- LDS bounce (per-wave [64][88] us region), coalesced probs store
  ushort* pw = lds + wid * 5632;
#pragma unroll
  for (int m = 0; m < 4; ++m)
#pragma unroll
    for (int n = 0; n < 5; ++n)
#pragma unroll
      for (int j = 0; j < 4; ++j)
        pw[(m * 16 + l4 * 4 + j) * 88 + n * 16 + l15] = f2bf(acc[m][n][j]);

  const uint* pw32 = (const uint*)pw;
  uint* probs32 = (uint*)probs;
  const int head = h0 + wN;
  const long sbase = (long)z * 4096 + s0 + wM * 64;
#pragma unroll 4
  for (int k = 0; k < 40; ++k) {
    int f2 = k * 64 + lane;
    int r = f2 / 40;
    int tp = f2 - r * 40;
    probs32[(sbase + r) * 320 + head * 40 + tp] = pw32[r * 44 + tp];
  }
#undef SS_GLB
#undef SS_LOADA
#undef SS_CVTW
#undef SS_MF
}

// ---------------- output GEMM: 256x256, BK=64, 8-phase-class schedule ----------------
// C[z][m][n] = sum_k P[z][m][k]*Nt[z][n][k] + bias[n]. M=4096, N=1280(5x256), K=640(10x64).
// LDS 128 KiB: 2 bufs x (A[256][64] | B[256][64]). Waves 2M x 4N: wave = 128x64.
__global__ __launch_bounds__(512, 1) void gemm_out(
    const ushort* __restrict__ P, const ushort* __restrict__ Nt,
    float* __restrict__ C, const float* __restrict__ bias)
{
  __shared__ ushort lds[65536];

  const int z = blockIdx.z;
  const ushort* Ab = P + (long)z * (4096L * 640) + (long)blockIdx.x * 256 * 640;
  const ushort* Bb = Nt + (long)z * (1280L * 640) + (long)blockIdx.y * 256 * 640;
  const int tid = threadIdx.x;
  const int lane = tid & 63;
  const int wid = tid >> 6;
  const int wM = wid >> 2;   // 0..1
  const int wN = wid & 3;    // 0..3
  const int l15 = lane & 15;
  const int l4 = lane >> 4;

  // staging: 4 instrs per operand per step; instr j covers rows j*64..+63
  const int r0 = tid >> 3, sl = tid & 7;
  long asrc[4], bsrc[4]; int adst[4], bdst[4];
#pragma unroll
  for (int j = 0; j < 4; ++j) {
    int rr = j * 64 + r0;
    asrc[j] = (long)rr * 640 + ((sl ^ (rr & 7)) * 8);
    bsrc[j] = asrc[j];
    adst[j] = j * 4096 + tid * 8;
    bdst[j] = 16384 + j * 4096 + tid * 8;
  }

  int aoff[2][8], boff[2][4];
#pragma unroll
  for (int kk = 0; kk < 2; ++kk) {
#pragma unroll
    for (int m = 0; m < 8; ++m) {
      int r = wM * 128 + m * 16 + l15;
      aoff[kk][m] = r * 64 + (((kk * 4 + l4) ^ (r & 7)) * 8);
    }
#pragma unroll
    for (int n = 0; n < 4; ++n) {
      int r = wN * 64 + n * 16 + l15;
      boff[kk][n] = 16384 + r * 64 + (((kk * 4 + l4) ^ (r & 7)) * 8);
    }
  }

  f32x4 acc[8][4] = {};

#define OG_STG(nb, kt, J0, J1) { \
    gload16(Ab + asrc[J0] + (kt), &lds[(nb) + adst[J0]]); \
    gload16(Ab + asrc[J1] + (kt), &lds[(nb) + adst[J1]]); \
    gload16(Bb + bsrc[J0] + (kt), &lds[(nb) + bdst[J0]]); \
    gload16(Bb + bsrc[J1] + (kt), &lds[(nb) + bdst[J1]]); }
#define OG_MF(MLO) { \
    __builtin_amdgcn_s_setprio(1); \
    _Pragma("unroll") \
    for (int q = 0; q < 4; ++q) \
      _Pragma("unroll") \
      for (int n = 0; n < 4; ++n) \
        acc[(MLO) + q][n] = MFMA(av[q], bfv[n], acc[(MLO) + q][n]); \
    __builtin_amdgcn_s_setprio(0); }

  // prologue
  OG_STG(0, 0, 0, 1)
  OG_STG(0, 0, 2, 3)
  VM0()
  BAR(); SB();

  for (int s = 0; s < 10; ++s) {
    const int cb = (s & 1) * 32768;
    const int nb = 32768 - cb;
    const int kt1 = (s + 1) * 64;
    const bool pre = (s + 1 < 10);
    bf16x8 av[4], bfv[4];

    // ---- p0: A mh0 k0 + B k0; stage half
#pragma unroll
    for (int q = 0; q < 4; ++q) av[q] = *(const bf16x8*)(&lds[cb + aoff[0][q]]);
#pragma unroll
    for (int n = 0; n < 4; ++n) bfv[n] = *(const bf16x8*)(&lds[cb + boff[0][n]]);
    if (pre) OG_STG(nb, kt1, 0, 1)
    SB(); BAR();
    LGK0()
    OG_MF(0)
    SB(); BAR();

    // ---- p1: A mh1 k0; stage rest
#pragma unroll
    for (int q = 0; q < 4; ++q) av[q] = *(const bf16x8*)(&lds[cb + aoff[0][q + 4]]);
    if (pre) OG_STG(nb, kt1, 2, 3)
    SB(); BAR();
    LGK0()
    OG_MF(4)
    SB(); BAR();

    // ---- p2: A mh0 k1 + B k1
#pragma unroll
    for (int q = 0; q < 4; ++q) av[q] = *(const bf16x8*)(&lds[cb + aoff[1][q]]);
#pragma unroll
    for (int n = 0; n < 4; ++n) bfv[n] = *(const bf16x8*)(&lds[cb + boff[1][n]]);
    SB(); BAR();
    LGK0()
    OG_MF(0)
    SB(); BAR();

    // ---- p3: A mh1 k1; drain stage
#pragma unroll
    for (int q = 0; q < 4; ++q) av[q] = *(const bf16x8*)(&lds[cb + aoff[1][q + 4]]);
    VM0()
    SB(); BAR();
    LGK0()
    OG_MF(4)
    SB(); BAR();
  }
#undef OG_STG
#undef OG_MF

  // ---- coalesced C write via per-wave LDS bounce ([16][68] f32)
  float* pw = (float*)lds + wid * 1088;
  const int ccol = blockIdx.y * 256 + wN * 64;
  const float4 bv4 = *(const float4*)(bias + ccol + l15 * 4);
  const long crow0 = (long)z * 4096 + blockIdx.x * 256 + wM * 128;
#pragma unroll
  for (int m = 0; m < 8; ++m) {
#pragma unroll
    for (int n = 0; n < 4; ++n)
#pragma unroll
      for (int j = 0; j < 4; ++j)
        pw[(l4 * 4 + j) * 68 + n * 16 + l15] = acc[m][n][j];
    asm volatile("s_waitcnt lgkmcnt(0)" ::: "memory"); SB();
#pragma unroll
    for (int pass = 0; pass < 4; ++pass) {
      int r = pass * 4 + l4;
      float4 v = *(const float4*)(pw + r * 68 + l15 * 4);
      v.x += bv4.x; v.y += bv4.y; v.z += bv4.z; v.w += bv4.w;
      *(float4*)(C + (crow0 + m * 16 + r) * 1280 + ccol + l15 * 4) = v;
    }
    asm volatile("s_waitcnt lgkmcnt(0)" ::: "memory"); SB();
  }
}

// Nt pad: zero cols h*80+77..79 for all b, j
__global__ void zero_nt_pad(ushort* __restrict__ Nt) {
  int idx = blockIdx.x * 256 + threadIdx.x;
  if (idx >= 8 * 1280 * 24) return;
  int b = idx / (1280 * 24);
  int rem = idx % (1280 * 24);
  int j = rem / 24, q = rem % 24;
  int h = q / 3, t = 77 + q % 3;
  Nt[(long)b * 1280 * 640 + (long)j * 640 + h * 80 + t] = 0;
}

extern "C" void kernel_launch(void* const* d_in, const int* in_sizes, int n_in,
                              void* d_out, int out_size, void* d_ws, size_t ws_size,
                              hipStream_t stream) {
  (void)in_sizes; (void)n_in; (void)out_size; (void)ws_size;
  const float* hs     = (const float*)d_in[0];
  const float* ehs    = (const float*)d_in[1];
  const float* Wq     = (const float*)d_in[2];
  const float* Wk     = (const float*)d_in[3];
  const float* Wv     = (const float*)d_in[4];
  const float* Wo     = (const float*)d_in[5];
  const float* bo     = (const float*)d_in[6];
  const float* q_down = (const float*)d_in[7];
  const float* q_up   = (const float*)d_in[8];
  const float* k_down = (const float*)d_in[9];
  const float* k_up   = (const float*)d_in[10];
  const float* v_down = (const float*)d_in[11];
  const float* v_up   = (const float*)d_in[12];
  const float* o_down = (const float*)d_in[13];
  const float* o_up   = (const float*)d_in[14];

  char* w = (char*)d_ws;
  size_t off = 0;
  auto alloc = [&](size_t b) { char* p = w + off; off = (off + b + 255) & ~(size_t)255; return p; };
  ushort* ehs_bf = (ushort*)alloc(616L * 768 * 2);
  ushort* WqT    = (ushort*)alloc(1280L * 1280 * 2);   // Wq_eff^T * inv_sqrt(DH)
  ushort* Wkv    = (ushort*)alloc(2560L * 768 * 2);    // [Wk_eff; Wv_eff]
  ushort* Wo_bf  = (ushort*)alloc(1280L * 1280 * 2);
  ushort* kv_bf  = (ushort*)alloc(616L * 2560 * 2);    // k | v
  ushort* Mt     = (ushort*)alloc(8L * 640 * 1280 * 2);
  ushort* Nt     = (ushort*)alloc(8L * 1280 * 640 * 2);  // col = h*80+t
  ushort* probs  = (ushort*)alloc(8L * 4096 * 640 * 2);  // col = h*80+t
  float*  outp   = (float*)d_out;
  const float invs = 0.07905694150420949f;  // 1/sqrt(160)

  // fold LoRA into effective weights (bf16)
  fold_kernel<<<6400, 256, 0, stream>>>(Wq, q_up, q_down, WqT, 1280, 1280, 1, invs);
  fold_kernel<<<3840, 256, 0, stream>>>(Wk, k_up, k_down, Wkv, 1280, 768, 0, 1.0f);
  fold_kernel<<<3840, 256, 0, stream>>>(Wv, v_up, v_down, Wkv + 1280L * 768, 1280, 768, 0, 1.0f);
  fold_kernel<<<6400, 256, 0, stream>>>(Wo, o_up, o_down, Wo_bf, 1280, 1280, 0, 1.0f);
  cvt_kernel<<<231, 256, 0, stream>>>(ehs, ehs_bf, 59136);
  // fused k|v projection: (616x768)@(768->2560), bf16 out
  gemm_bt<<<dim3(5, 20, 1), 256, 0, stream>>>(ehs_bf, 0, 0, 768, 616,
      Wkv, 0, 0, 768, 2560, nullptr, kv_bf, 0, 0, 2560, nullptr, 768);
  // Mt[b][h*77+t][i] = inv_sqrt * sum_d k[b,t,h*160+d] * Wq_eff[h*160+d][i]   (z = b*8+h)
  gemm_bt<<<dim3(1, 10, 64), 256, 0, stream>>>(kv_bf, 77L * 2560, 160, 2560, 77,
      WqT, 0, 160, 1280, 1280, nullptr, Mt, 640L * 1280, 77L * 1280, 1280, nullptr, 160);
  // Nt[b][j][h*80+t] = sum_d Wo_eff[j][h*160+d] * v[b,t,h*160+d]
  gemm_bt<<<dim3(10, 1, 64), 256, 0, stream>>>(Wo_bf, 0, 160, 1280, 1280,
      kv_bf + 1280, 77L * 2560, 160, 2560, 77, nullptr, Nt, 1280L * 640, 80, 640, nullptr, 160);
  zero_nt_pad<<<960, 256, 0, stream>>>(Nt);
  // fused scores + softmax -> probs bf16
  score_softmax<<<dim3(16, 4, 8), 512, 0, stream>>>(hs, Mt, probs);
  // out = probs @ Nt^T + bo
  gemm_out<<<dim3(16, 5, 8), 512, 0, stream>>>(probs, Nt, outp, bo);
}

// Round 7
// 286.233 us; speedup vs baseline: 1.2665x; 1.2665x over previous
//
#include <hip/hip_runtime.h>
#include <hip/hip_bf16.h>
#include <stdint.h>

typedef short bf16x8 __attribute__((ext_vector_type(8)));
typedef float f32x4 __attribute__((ext_vector_type(4)));

#define DEVI static __device__ __forceinline__

DEVI ushort f2bf(float f) {
  union { float f; uint32_t u; } v; v.f = f;
  uint32_t u = v.u;
  return (ushort)((u + 0x7fffu + ((u >> 16) & 1u)) >> 16);
}

DEVI void gload16(const void* g, void* l) {
  __builtin_amdgcn_global_load_lds((const __attribute__((address_space(1))) void*)g,
                                   (__attribute__((address_space(3))) void*)l,
                                   16, 0, 0);
}

#define SB() __builtin_amdgcn_sched_barrier(0)
#define BAR() __builtin_amdgcn_s_barrier()
#define MFMA(a, b, c) __builtin_amdgcn_mfma_f32_16x16x32_bf16((a), (b), (c), 0, 0, 0)

// ---------------- weight fold / convert ----------------

__global__ void fold_kernel(const float* __restrict__ W, const float* __restrict__ up,
                            const float* __restrict__ down, ushort* __restrict__ out,
                            int OUT, int IN, int transpose, float scale) {
  int idx = blockIdx.x * 256 + threadIdx.x;
  if (idx >= OUT * IN) return;
  int o = idx / IN, i = idx % IN;
  float v = W[idx];
#pragma unroll
  for (int r = 0; r < 4; ++r) v += up[o * 4 + r] * down[r * IN + i];
  v *= scale;
  out[transpose ? ((long)i * OUT + o) : idx] = f2bf(v);
}

__global__ void cvt_kernel(const float* __restrict__ in, ushort* __restrict__ out, int n8) {
  int idx = blockIdx.x * 256 + threadIdx.x;
  if (idx >= n8) return;
  const float4* p = (const float4*)(in + (long)idx * 8);
  float4 a = p[0], b = p[1];
  union { ushort us[8]; uint4 v; } r;
  r.us[0] = f2bf(a.x); r.us[1] = f2bf(a.y); r.us[2] = f2bf(a.z); r.us[3] = f2bf(a.w);
  r.us[4] = f2bf(b.x); r.us[5] = f2bf(b.y); r.us[6] = f2bf(b.z); r.us[7] = f2bf(b.w);
  *(uint4*)(out + (long)idx * 8) = r.v;
}

// ---------------- small-GEMM kernel (128x128, BK=32) — proven ----------------

__global__ __launch_bounds__(256) void gemm_bt(
    const ushort* __restrict__ A, long sA0, long sA1, int lda, int validM,
    const ushort* __restrict__ B, long sB0, long sB1, int ldb, int validN,
    float* __restrict__ C32, ushort* __restrict__ C16, long sC0, long sC1, int ldc,
    const float* __restrict__ bias, int K)
{
  __shared__ ushort As[128 * 32];
  __shared__ ushort Bs[128 * 32];

  const int z = blockIdx.z;
  const ushort* Ab = A + (long)(z >> 3) * sA0 + (long)(z & 7) * sA1;
  const ushort* Bb = B + (long)(z >> 3) * sB0 + (long)(z & 7) * sB1;
  const int m0 = blockIdx.x * 128;
  const int n0 = blockIdx.y * 128;
  const int tid = threadIdx.x;
  const int lane = tid & 63;
  const int wid = tid >> 6;

  const int c0 = tid;
  const int arow0 = min(m0 + (c0 >> 2), validM - 1);
  const int arow1 = min(m0 + (c0 >> 2) + 64, validM - 1);
  const int brow0 = min(n0 + (c0 >> 2), validN - 1);
  const int brow1 = min(n0 + (c0 >> 2) + 64, validN - 1);
  const int seg = (c0 & 3) * 8;

  const int wr = (wid >> 1) * 64;
  const int wc = (wid & 1) * 64;
  const int frow = lane & 15;
  const int fk = (lane >> 4) * 8;

  f32x4 acc[4][4] = {};

  for (int kt = 0; kt < K; kt += 32) {
    gload16(Ab + (long)arow0 * lda + kt + seg, As + c0 * 8);
    gload16(Ab + (long)arow1 * lda + kt + seg, As + (c0 + 256) * 8);
    gload16(Bb + (long)brow0 * ldb + kt + seg, Bs + c0 * 8);
    gload16(Bb + (long)brow1 * ldb + kt + seg, Bs + (c0 + 256) * 8);
    __syncthreads();

    bf16x8 af[4], bfr[4];
#pragma unroll
    for (int m = 0; m < 4; ++m)
      af[m] = *(const bf16x8*)(As + (wr + m * 16 + frow) * 32 + fk);
#pragma unroll
    for (int n = 0; n < 4; ++n)
      bfr[n] = *(const bf16x8*)(Bs + (wc + n * 16 + frow) * 32 + fk);
#pragma unroll
    for (int m = 0; m < 4; ++m)
#pragma unroll
      for (int n = 0; n < 4; ++n)
        acc[m][n] = MFMA(af[m], bfr[n], acc[m][n]);
    __syncthreads();
  }

  const long cb = (long)(z >> 3) * sC0 + (long)(z & 7) * sC1;
  const int crow = m0 + wr + (lane >> 4) * 4;
  const int ccol = n0 + wc + (lane & 15);
#pragma unroll
  for (int m = 0; m < 4; ++m)
#pragma unroll
    for (int n = 0; n < 4; ++n)
#pragma unroll
      for (int j = 0; j < 4; ++j) {
        int r = crow + m * 16 + j;
        int c = ccol + n * 16;
        if (r < validM && c < validN) {
          float v = acc[m][n][j];
          if (bias) v += bias[c];
          if (C32) C32[cb + (long)r * ldc + c] = v;
          else     C16[cb + (long)r * ldc + c] = f2bf(v);
        }
      }
}

// ---------------- fused scores GEMM + softmax (r2 skeleton, 2 blocks/CU) ----------------
// Tile 128 rows x 192 cols (2 heads x 96), 256 thr (4 waves 2Mx2N), z = batch.
// Wave = 64 rows x 96 cols = one full head -> wave-local softmax (proven r4/r5).
// K = 1280 = 20 steps of BK=64. LDS: 2 bufs x (A[128][64] | B[192][64]) = 80 KiB.
// 8-slot XOR swizzle: linear LDS dest, pre-swizzled global source (rule #21).
// Counted vmcnt(10): next tile's 10 loads stay in flight across the barrier (T4).
__global__ __launch_bounds__(256, 2) void score_softmax(
    const ushort* __restrict__ hsb, const ushort* __restrict__ Mt,
    ushort* __restrict__ probs)
{
  __shared__ ushort lds[40960];  // 2 x 20480 us (A 8192 | B 12288)

  const int z = blockIdx.z;
  const int s0 = blockIdx.x * 128;
  const int h0 = blockIdx.y * 2;
  const int tid = threadIdx.x;
  const int lane = tid & 63;
  const int wid = tid >> 6;
  const int wM = wid >> 1;                  // 0..1
  const int wN = wid & 1;                   // 0..1
  const int l15 = lane & 15;
  const int l4 = lane >> 4;
  const int sl = tid & 7;

  // A staging: 4 gload16, instr j covers rows j*32..j*32+31
  const ushort* Ag = hsb + ((long)z * 4096 + s0) * 1280;
  long asrc[4]; int adst[4];
#pragma unroll
  for (int j = 0; j < 4; ++j) {
    int r = j * 32 + (tid >> 3);
    asrc[j] = (long)r * 1280 + ((sl ^ (r & 7)) * 8);
    adst[j] = (j * 256 + tid) * 8;
  }
  // B staging: 6 gload16 (192 rows), head-mapped with t clamped to 76
  const ushort* Bg = Mt + (long)z * (640L * 1280);
  long bsrc[6]; int bdst[6];
#pragma unroll
  for (int j = 0; j < 6; ++j) {
    int rb = j * 32 + (tid >> 3);
    int c = h0 * 96 + rb;
    int hh = c / 96, tt = min(c - hh * 96, 76);
    bsrc[j] = (long)(hh * 77 + tt) * 1280 + ((sl ^ (rb & 7)) * 8);
    bdst[j] = 8192 + (j * 256 + tid) * 8;
  }

  // fragment offsets
  int aoff[2][4], boff[2][6];
#pragma unroll
  for (int kk = 0; kk < 2; ++kk) {
#pragma unroll
    for (int m = 0; m < 4; ++m) {
      int r = wM * 64 + m * 16 + l15;
      aoff[kk][m] = r * 64 + (((kk * 4 + l4) ^ (r & 7)) * 8);
    }
#pragma unroll
    for (int n = 0; n < 6; ++n) {
      int r = wN * 96 + n * 16 + l15;
      boff[kk][n] = 8192 + r * 64 + (((kk * 4 + l4) ^ (r & 7)) * 8);
    }
  }

  f32x4 acc[4][6] = {};

#define SS_STAGE(bb, kt) { \
    _Pragma("unroll") for (int j = 0; j < 4; ++j) gload16(Ag + asrc[j] + (kt), &lds[(bb) + adst[j]]); \
    _Pragma("unroll") for (int j = 0; j < 6; ++j) gload16(Bg + bsrc[j] + (kt), &lds[(bb) + bdst[j]]); }

  SS_STAGE(0, 0)

  for (int t = 0; t < 20; ++t) {
    const int base = (t & 1) * 20480;
    if (t + 1 < 20) {
      SS_STAGE(20480 - base, (t + 1) * 64)
      asm volatile("s_waitcnt vmcnt(10)" ::: "memory");
    } else {
      asm volatile("s_waitcnt vmcnt(0)" ::: "memory");
    }
    SB(); BAR(); SB();
#pragma unroll
    for (int kk = 0; kk < 2; ++kk) {
      bf16x8 av[4], bv[6];
#pragma unroll
      for (int m = 0; m < 4; ++m) av[m] = *(const bf16x8*)(&lds[base + aoff[kk][m]]);
#pragma unroll
      for (int n = 0; n < 6; ++n) bv[n] = *(const bf16x8*)(&lds[base + boff[kk][n]]);
      __builtin_amdgcn_s_setprio(1);
#pragma unroll
      for (int m = 0; m < 4; ++m)
#pragma unroll
        for (int n = 0; n < 6; ++n)
          acc[m][n] = MFMA(av[m], bv[n], acc[m][n]);
      __builtin_amdgcn_s_setprio(0);
    }
    SB(); BAR();
  }
#undef SS_STAGE

  // ---- wave-local softmax over 77 valid cols
#pragma unroll
  for (int m = 0; m < 4; ++m)
#pragma unroll
    for (int j = 0; j < 4; ++j) {
      float mx = -1e30f;
#pragma unroll
      for (int n = 0; n < 6; ++n)
        if (n * 16 + l15 < 77) mx = fmaxf(mx, acc[m][n][j]);
#pragma unroll
      for (int o = 8; o; o >>= 1) mx = fmaxf(mx, __shfl_xor(mx, o));
      float sum = 0.f;
#pragma unroll
      for (int n = 0; n < 6; ++n) {
        float e = (n * 16 + l15 < 77) ? __expf(acc[m][n][j] - mx) : 0.f;
        acc[m][n][j] = e;
        sum += e;
      }
#pragma unroll
      for (int o = 8; o; o >>= 1) sum += __shfl_xor(sum, o);
      float inv = 1.f / sum;
#pragma unroll
      for (int n = 0; n < 6; ++n) acc[m][n][j] *= inv;
    }

  // ---- per-wave LDS bounce ([64][88] us), coalesced probs store (proven r5)
  __syncthreads();
  ushort* pw = lds + wid * 5632;
#pragma unroll
  for (int m = 0; m < 4; ++m)
#pragma unroll
    for (int n = 0; n < 5; ++n)
#pragma unroll
      for (int j = 0; j < 4; ++j)
        pw[(m * 16 + l4 * 4 + j) * 88 + n * 16 + l15] = f2bf(acc[m][n][j]);

  const uint* pw32 = (const uint*)pw;
  uint* probs32 = (uint*)probs;
  const int head = h0 + wN;
  const long sbase = (long)z * 4096 + s0 + wM * 64;
#pragma unroll 4
  for (int k = 0; k < 40; ++k) {
    int f2 = k * 64 + lane;
    int r = f2 / 40;
    int tp = f2 - r * 40;
    probs32[(sbase + r) * 320 + head * 40 + tp] = pw32[r * 44 + tp];
  }
}

// ---------------- output GEMM: 128x128, BK=64, r2 skeleton, 2+ blocks/CU ----------------
// C[z][m][n] = sum_k P[z][m][k]*Nt[z][n][k] + bias[n]. M=4096, N=1280, K=640 (10 steps).
// LDS: 2 bufs x (A[128][64] | B[128][64]) = 64 KiB. Counted vmcnt(8).
__global__ __launch_bounds__(256, 2) void gemm_out(
    const ushort* __restrict__ P, const ushort* __restrict__ Nt,
    float* __restrict__ C, const float* __restrict__ bias)
{
  __shared__ ushort lds[32768];  // 2 x 16384 us (A 8192 | B 8192)

  const int z = blockIdx.z;
  const ushort* Ab = P + (long)z * (4096L * 640) + (long)blockIdx.x * 128 * 640;
  const ushort* Bb = Nt + (long)z * (1280L * 640) + (long)blockIdx.y * 128 * 640;
  const int tid = threadIdx.x;
  const int lane = tid & 63;
  const int wid = tid >> 6;
  const int wM = wid >> 1;   // 0..1
  const int wN = wid & 1;    // 0..1
  const int l15 = lane & 15;
  const int l4 = lane >> 4;
  const int sl = tid & 7;

  long asrc[4]; int adst[4], bdst[4];
#pragma unroll
  for (int j = 0; j < 4; ++j) {
    int r = j * 32 + (tid >> 3);
    asrc[j] = (long)r * 640 + ((sl ^ (r & 7)) * 8);   // same for A and B (both 128 rows, ld 640)
    adst[j] = (j * 256 + tid) * 8;
    bdst[j] = 8192 + (j * 256 + tid) * 8;
  }

  int aoff[2][4], boff[2][4];
#pragma unroll
  for (int kk = 0; kk < 2; ++kk) {
#pragma unroll
    for (int m = 0; m < 4; ++m) {
      int r = wM * 64 + m * 16 + l15;
      aoff[kk][m] = r * 64 + (((kk * 4 + l4) ^ (r & 7)) * 8);
    }
#pragma unroll
    for (int n = 0; n < 4; ++n) {
      int r = wN * 64 + n * 16 + l15;
      boff[kk][n] = 8192 + r * 64 + (((kk * 4 + l4) ^ (r & 7)) * 8);
    }
  }

  f32x4 acc[4][4] = {};

#define OG_STAGE(bb, kt) { \
    _Pragma("unroll") for (int j = 0; j < 4; ++j) gload16(Ab + asrc[j] + (kt), &lds[(bb) + adst[j]]); \
    _Pragma("unroll") for (int j = 0; j < 4; ++j) gload16(Bb + asrc[j] + (kt), &lds[(bb) + bdst[j]]); }

  OG_STAGE(0, 0)

  for (int t = 0; t < 10; ++t) {
    const int base = (t & 1) * 16384;
    if (t + 1 < 10) {
      OG_STAGE(16384 - base, (t + 1) * 64)
      asm volatile("s_waitcnt vmcnt(8)" ::: "memory");
    } else {
      asm volatile("s_waitcnt vmcnt(0)" ::: "memory");
    }
    SB(); BAR(); SB();
#pragma unroll
    for (int kk = 0; kk < 2; ++kk) {
      bf16x8 av[4], bv[4];
#pragma unroll
      for (int m = 0; m < 4; ++m) av[m] = *(const bf16x8*)(&lds[base + aoff[kk][m]]);
#pragma unroll
      for (int n = 0; n < 4; ++n) bv[n] = *(const bf16x8*)(&lds[base + boff[kk][n]]);
      __builtin_amdgcn_s_setprio(1);
#pragma unroll
      for (int m = 0; m < 4; ++m)
#pragma unroll
        for (int n = 0; n < 4; ++n)
          acc[m][n] = MFMA(av[m], bv[n], acc[m][n]);
      __builtin_amdgcn_s_setprio(0);
    }
    SB(); BAR();
  }
#undef OG_STAGE

  // ---- coalesced C write via per-wave LDS bounce ([16][68] f32)
  __syncthreads();
  float* pw = (float*)lds + wid * 1088;
  const int ccol = blockIdx.y * 128 + wN * 64;
  const float4 bv4 = *(const float4*)(bias + ccol + l15 * 4);
  const long crow0 = (long)z * 4096 + blockIdx.x * 128 + wM * 64;
#pragma unroll
  for (int m = 0; m < 4; ++m) {
#pragma unroll
    for (int n = 0; n < 4; ++n)
#pragma unroll
      for (int j = 0; j < 4; ++j)
        pw[(l4 * 4 + j) * 68 + n * 16 + l15] = acc[m][n][j];
    asm volatile("s_waitcnt lgkmcnt(0)" ::: "memory"); SB();
#pragma unroll
    for (int pass = 0; pass < 4; ++pass) {
      int r = pass * 4 + l4;
      float4 v = *(const float4*)(pw + r * 68 + l15 * 4);
      v.x += bv4.x; v.y += bv4.y; v.z += bv4.z; v.w += bv4.w;
      *(float4*)(C + (crow0 + m * 16 + r) * 1280 + ccol + l15 * 4) = v;
    }
    asm volatile("s_waitcnt lgkmcnt(0)" ::: "memory"); SB();
  }
}

// Nt pad: zero cols h*80+77..79 for all b, j
__global__ void zero_nt_pad(ushort* __restrict__ Nt) {
  int idx = blockIdx.x * 256 + threadIdx.x;
  if (idx >= 8 * 1280 * 24) return;
  int b = idx / (1280 * 24);
  int rem = idx % (1280 * 24);
  int j = rem / 24, q = rem % 24;
  int h = q / 3, t = 77 + q % 3;
  Nt[(long)b * 1280 * 640 + (long)j * 640 + h * 80 + t] = 0;
}

extern "C" void kernel_launch(void* const* d_in, const int* in_sizes, int n_in,
                              void* d_out, int out_size, void* d_ws, size_t ws_size,
                              hipStream_t stream) {
  (void)in_sizes; (void)n_in; (void)out_size; (void)ws_size;
  const float* hs     = (const float*)d_in[0];
  const float* ehs    = (const float*)d_in[1];
  const float* Wq     = (const float*)d_in[2];
  const float* Wk     = (const float*)d_in[3];
  const float* Wv     = (const float*)d_in[4];
  const float* Wo     = (const float*)d_in[5];
  const float* bo     = (const float*)d_in[6];
  const float* q_down = (const float*)d_in[7];
  const float* q_up   = (const float*)d_in[8];
  const float* k_down = (const float*)d_in[9];
  const float* k_up   = (const float*)d_in[10];
  const float* v_down = (const float*)d_in[11];
  const float* v_up   = (const float*)d_in[12];
  const float* o_down = (const float*)d_in[13];
  const float* o_up   = (const float*)d_in[14];

  char* w = (char*)d_ws;
  size_t off = 0;
  auto alloc = [&](size_t b) { char* p = w + off; off = (off + b + 255) & ~(size_t)255; return p; };
  ushort* hs_bf  = (ushort*)alloc(32768L * 1280 * 2);
  ushort* ehs_bf = (ushort*)alloc(616L * 768 * 2);
  ushort* WqT    = (ushort*)alloc(1280L * 1280 * 2);   // Wq_eff^T * inv_sqrt(DH)
  ushort* Wkv    = (ushort*)alloc(2560L * 768 * 2);    // [Wk_eff; Wv_eff]
  ushort* Wo_bf  = (ushort*)alloc(1280L * 1280 * 2);
  ushort* kv_bf  = (ushort*)alloc(616L * 2560 * 2);    // k | v
  ushort* Mt     = (ushort*)alloc(8L * 640 * 1280 * 2);
  ushort* Nt     = (ushort*)alloc(8L * 1280 * 640 * 2);  // col = h*80+t
  ushort* probs  = (ushort*)alloc(8L * 4096 * 640 * 2);  // col = h*80+t
  float*  outp   = (float*)d_out;
  const float invs = 0.07905694150420949f;  // 1/sqrt(160)

  // fold LoRA into effective weights (bf16)
  fold_kernel<<<6400, 256, 0, stream>>>(Wq, q_up, q_down, WqT, 1280, 1280, 1, invs);
  fold_kernel<<<3840, 256, 0, stream>>>(Wk, k_up, k_down, Wkv, 1280, 768, 0, 1.0f);
  fold_kernel<<<3840, 256, 0, stream>>>(Wv, v_up, v_down, Wkv + 1280L * 768, 1280, 768, 0, 1.0f);
  fold_kernel<<<6400, 256, 0, stream>>>(Wo, o_up, o_down, Wo_bf, 1280, 1280, 0, 1.0f);
  cvt_kernel<<<20480, 256, 0, stream>>>(hs, hs_bf, 5242880);
  cvt_kernel<<<231, 256, 0, stream>>>(ehs, ehs_bf, 59136);
  // fused k|v projection: (616x768)@(768->2560), bf16 out
  gemm_bt<<<dim3(5, 20, 1), 256, 0, stream>>>(ehs_bf, 0, 0, 768, 616,
      Wkv, 0, 0, 768, 2560, nullptr, kv_bf, 0, 0, 2560, nullptr, 768);
  // Mt[b][h*77+t][i] = inv_sqrt * sum_d k[b,t,h*160+d] * Wq_eff[h*160+d][i]   (z = b*8+h)
  gemm_bt<<<dim3(1, 10, 64), 256, 0, stream>>>(kv_bf, 77L * 2560, 160, 2560, 77,
      WqT, 0, 160, 1280, 1280, nullptr, Mt, 640L * 1280, 77L * 1280, 1280, nullptr, 160);
  // Nt[b][j][h*80+t] = sum_d Wo_eff[j][h*160+d] * v[b,t,h*160+d]
  gemm_bt<<<dim3(10, 1, 64), 256, 0, stream>>>(Wo_bf, 0, 160, 1280, 1280,
      kv_bf + 1280, 77L * 2560, 160, 2560, 77, nullptr, Nt, 1280L * 640, 80, 640, nullptr, 160);
  zero_nt_pad<<<960, 256, 0, stream>>>(Nt);
  // fused scores + softmax -> probs bf16 (col = h*80+t)
  score_softmax<<<dim3(32, 4, 8), 256, 0, stream>>>(hs_bf, Mt, probs);
  // out = probs @ Nt^T + bo
  gemm_out<<<dim3(32, 10, 8), 256, 0, stream>>>(probs, Nt, outp, bo);
}

// Round 8
// 280.552 us; speedup vs baseline: 1.2921x; 1.0202x over previous
//
#include <hip/hip_runtime.h>
#include <hip/hip_bf16.h>
#include <stdint.h>

typedef short bf16x8 __attribute__((ext_vector_type(8)));
typedef float f32x4 __attribute__((ext_vector_type(4)));

#define DEVI static __device__ __forceinline__

DEVI ushort f2bf(float f) {
  union { float f; uint32_t u; } v; v.f = f;
  uint32_t u = v.u;
  return (ushort)((u + 0x7fffu + ((u >> 16) & 1u)) >> 16);
}

DEVI void gload16(const void* g, void* l) {
  __builtin_amdgcn_global_load_lds((const __attribute__((address_space(1))) void*)g,
                                   (__attribute__((address_space(3))) void*)l,
                                   16, 0, 0);
}

#define SB() __builtin_amdgcn_sched_barrier(0)
#define BAR() __builtin_amdgcn_s_barrier()
#define MFMA(a, b, c) __builtin_amdgcn_mfma_f32_16x16x32_bf16((a), (b), (c), 0, 0, 0)
// BK=32 swizzle key: 4 slots/row, 2-level XOR -> exactly 2-way bank aliasing (free, m136)
#define KEY4(r) ((((r) & 3)) ^ (((r) >> 2) & 3))

// ---------------- fused prep: cvt_hs | cvt_ehs | 4x fold | Nt-pad-zero ----------------
// All regions independent (read inputs only, write disjoint ws regions).
__global__ __launch_bounds__(256) void prep_fused(
    const float* __restrict__ hs, ushort* __restrict__ hs_bf,
    const float* __restrict__ ehs, ushort* __restrict__ ehs_bf,
    const float* __restrict__ Wq, const float* __restrict__ q_up, const float* __restrict__ q_down,
    ushort* __restrict__ WqT,
    const float* __restrict__ Wk, const float* __restrict__ k_up, const float* __restrict__ k_down,
    const float* __restrict__ Wv, const float* __restrict__ v_up, const float* __restrict__ v_down,
    ushort* __restrict__ Wkv,
    const float* __restrict__ Wo, const float* __restrict__ o_up, const float* __restrict__ o_down,
    ushort* __restrict__ Wo_bf,
    ushort* __restrict__ Nt, float invs)
{
  const int b = blockIdx.x;
  const int tid = threadIdx.x;
  if (b < 20480) {                       // cvt_hs: 5242880 chunks of 8 f32
    long idx = (long)b * 256 + tid;
    const float4* p = (const float4*)(hs + idx * 8);
    float4 a = p[0], c = p[1];
    union { ushort us[8]; uint4 v; } r;
    r.us[0] = f2bf(a.x); r.us[1] = f2bf(a.y); r.us[2] = f2bf(a.z); r.us[3] = f2bf(a.w);
    r.us[4] = f2bf(c.x); r.us[5] = f2bf(c.y); r.us[6] = f2bf(c.z); r.us[7] = f2bf(c.w);
    *(uint4*)(hs_bf + idx * 8) = r.v;
  } else if (b < 20711) {                // cvt_ehs: 59136 chunks
    int idx = (b - 20480) * 256 + tid;
    if (idx < 59136) {
      const float4* p = (const float4*)(ehs + (long)idx * 8);
      float4 a = p[0], c = p[1];
      union { ushort us[8]; uint4 v; } r;
      r.us[0] = f2bf(a.x); r.us[1] = f2bf(a.y); r.us[2] = f2bf(a.z); r.us[3] = f2bf(a.w);
      r.us[4] = f2bf(c.x); r.us[5] = f2bf(c.y); r.us[6] = f2bf(c.z); r.us[7] = f2bf(c.w);
      *(uint4*)(ehs_bf + (long)idx * 8) = r.v;
    }
  } else if (b < 41191) {                // folds: 5242880 elements across 4 weights
    long f = (long)(b - 20711) * 256 + tid;
    const float *W, *up, *down; ushort* out;
    int OUT, IN, transpose; float scale; long base;
    if (f < 1638400)        { base = f;           W = Wq; up = q_up; down = q_down; out = WqT;   OUT = 1280; IN = 1280; transpose = 1; scale = invs; }
    else if (f < 2621440)   { base = f - 1638400; W = Wk; up = k_up; down = k_down; out = Wkv;   OUT = 1280; IN = 768;  transpose = 0; scale = 1.f; }
    else if (f < 3604480)   { base = f - 2621440; W = Wv; up = v_up; down = v_down; out = Wkv + 1280L * 768; OUT = 1280; IN = 768; transpose = 0; scale = 1.f; }
    else                    { base = f - 3604480; W = Wo; up = o_up; down = o_down; out = Wo_bf; OUT = 1280; IN = 1280; transpose = 0; scale = 1.f; }
    int o = (int)(base / IN), i = (int)(base % IN);
    float v = W[base];
#pragma unroll
    for (int r = 0; r < 4; ++r) v += up[o * 4 + r] * down[r * IN + i];
    v *= scale;
    out[transpose ? ((long)i * OUT + o) : base] = f2bf(v);
  } else {                               // Nt pad zero: 8*1280*24 = 245760
    int idx = (b - 41191) * 256 + tid;
    int bb = idx / (1280 * 24);
    int rem = idx % (1280 * 24);
    int j = rem / 24, q = rem % 24;
    int h = q / 3, t = 77 + q % 3;
    Nt[(long)bb * 1280 * 640 + (long)j * 640 + h * 80 + t] = 0;
  }
}

// ---------------- small-GEMM kernel (128x128, BK=32) — proven ----------------

__global__ __launch_bounds__(256) void gemm_bt(
    const ushort* __restrict__ A, long sA0, long sA1, int lda, int validM,
    const ushort* __restrict__ B, long sB0, long sB1, int ldb, int validN,
    float* __restrict__ C32, ushort* __restrict__ C16, long sC0, long sC1, int ldc,
    const float* __restrict__ bias, int K)
{
  __shared__ ushort As[128 * 32];
  __shared__ ushort Bs[128 * 32];

  const int z = blockIdx.z;
  const ushort* Ab = A + (long)(z >> 3) * sA0 + (long)(z & 7) * sA1;
  const ushort* Bb = B + (long)(z >> 3) * sB0 + (long)(z & 7) * sB1;
  const int m0 = blockIdx.x * 128;
  const int n0 = blockIdx.y * 128;
  const int tid = threadIdx.x;
  const int lane = tid & 63;
  const int wid = tid >> 6;

  const int c0 = tid;
  const int arow0 = min(m0 + (c0 >> 2), validM - 1);
  const int arow1 = min(m0 + (c0 >> 2) + 64, validM - 1);
  const int brow0 = min(n0 + (c0 >> 2), validN - 1);
  const int brow1 = min(n0 + (c0 >> 2) + 64, validN - 1);
  const int seg = (c0 & 3) * 8;

  const int wr = (wid >> 1) * 64;
  const int wc = (wid & 1) * 64;
  const int frow = lane & 15;
  const int fk = (lane >> 4) * 8;

  f32x4 acc[4][4] = {};

  for (int kt = 0; kt < K; kt += 32) {
    gload16(Ab + (long)arow0 * lda + kt + seg, As + c0 * 8);
    gload16(Ab + (long)arow1 * lda + kt + seg, As + (c0 + 256) * 8);
    gload16(Bb + (long)brow0 * ldb + kt + seg, Bs + c0 * 8);
    gload16(Bb + (long)brow1 * ldb + kt + seg, Bs + (c0 + 256) * 8);
    __syncthreads();

    bf16x8 af[4], bfr[4];
#pragma unroll
    for (int m = 0; m < 4; ++m)
      af[m] = *(const bf16x8*)(As + (wr + m * 16 + frow) * 32 + fk);
#pragma unroll
    for (int n = 0; n < 4; ++n)
      bfr[n] = *(const bf16x8*)(Bs + (wc + n * 16 + frow) * 32 + fk);
#pragma unroll
    for (int m = 0; m < 4; ++m)
#pragma unroll
      for (int n = 0; n < 4; ++n)
        acc[m][n] = MFMA(af[m], bfr[n], acc[m][n]);
    __syncthreads();
  }

  const long cb = (long)(z >> 3) * sC0 + (long)(z & 7) * sC1;
  const int crow = m0 + wr + (lane >> 4) * 4;
  const int ccol = n0 + wc + (lane & 15);
#pragma unroll
  for (int m = 0; m < 4; ++m)
#pragma unroll
    for (int n = 0; n < 4; ++n)
#pragma unroll
      for (int j = 0; j < 4; ++j) {
        int r = crow + m * 16 + j;
        int c = ccol + n * 16;
        if (r < validM && c < validN) {
          float v = acc[m][n][j];
          if (bias) v += bias[c];
          if (C32) C32[cb + (long)r * ldc + c] = v;
          else     C16[cb + (long)r * ldc + c] = f2bf(v);
        }
      }
}

// ---------------- fused scores GEMM + softmax (BK=32, ~3 blocks/CU) ----------------
// Tile 128 rows x 192 cols (2 heads x 96), 256 thr (4 waves 2Mx2N), z = batch.
// Wave = 64 rows x 96 cols = one full head -> wave-local softmax.
// K = 1280 = 40 steps of BK=32. LDS: 2 bufs x (A[128][32] | B[192][32]) = 40 KiB
// (+ bounce overlap; array sized 44 KiB). Counted vmcnt(5).
__global__ __launch_bounds__(256, 2) void score_softmax(
    const ushort* __restrict__ hsb, const ushort* __restrict__ Mt,
    ushort* __restrict__ probs)
{
  __shared__ ushort lds[22528];  // staging 2x10240; bounce 4x5632 (after syncthreads)

  const int z = blockIdx.z;
  const int s0 = blockIdx.x * 128;
  const int h0 = blockIdx.y * 2;
  const int tid = threadIdx.x;
  const int lane = tid & 63;
  const int wid = tid >> 6;
  const int wM = wid >> 1;                  // 0..1
  const int wN = wid & 1;                   // 0..1
  const int l15 = lane & 15;
  const int l4 = lane >> 4;
  const int sl = tid & 3;

  // A staging: 2 gload16, instr j covers rows j*64..j*64+63
  const ushort* Ag = hsb + ((long)z * 4096 + s0) * 1280;
  long asrc[2]; int adst[2];
#pragma unroll
  for (int j = 0; j < 2; ++j) {
    int r = j * 64 + (tid >> 2);
    asrc[j] = (long)r * 1280 + ((sl ^ KEY4(r)) * 8);
    adst[j] = (j * 256 + tid) * 8;
  }
  // B staging: 3 gload16 (192 rows), head-mapped with t clamped to 76
  const ushort* Bg = Mt + (long)z * (640L * 1280);
  long bsrc[3]; int bdst[3];
#pragma unroll
  for (int j = 0; j < 3; ++j) {
    int rb = j * 64 + (tid >> 2);
    int c = h0 * 96 + rb;
    int hh = c / 96, tt = min(c - hh * 96, 76);
    bsrc[j] = (long)(hh * 77 + tt) * 1280 + ((sl ^ KEY4(rb)) * 8);
    bdst[j] = 4096 + (j * 256 + tid) * 8;
  }

  // fragment offsets (single K=32 slice per step)
  int aoff[4], boff[6];
#pragma unroll
  for (int m = 0; m < 4; ++m) {
    int r = wM * 64 + m * 16 + l15;
    aoff[m] = r * 32 + ((l4 ^ KEY4(r)) * 8);
  }
#pragma unroll
  for (int n = 0; n < 6; ++n) {
    int r = wN * 96 + n * 16 + l15;
    boff[n] = 4096 + r * 32 + ((l4 ^ KEY4(r)) * 8);
  }

  f32x4 acc[4][6] = {};

#define SS_STAGE(bb, kt) { \
    _Pragma("unroll") for (int j = 0; j < 2; ++j) gload16(Ag + asrc[j] + (kt), &lds[(bb) + adst[j]]); \
    _Pragma("unroll") for (int j = 0; j < 3; ++j) gload16(Bg + bsrc[j] + (kt), &lds[(bb) + bdst[j]]); }

  SS_STAGE(0, 0)

  for (int t = 0; t < 40; ++t) {
    const int base = (t & 1) * 10240;
    if (t + 1 < 40) {
      SS_STAGE(10240 - base, (t + 1) * 32)
      asm volatile("s_waitcnt vmcnt(5)" ::: "memory");
    } else {
      asm volatile("s_waitcnt vmcnt(0)" ::: "memory");
    }
    SB(); BAR(); SB();
    bf16x8 av[4], bv[6];
#pragma unroll
    for (int m = 0; m < 4; ++m) av[m] = *(const bf16x8*)(&lds[base + aoff[m]]);
#pragma unroll
    for (int n = 0; n < 6; ++n) bv[n] = *(const bf16x8*)(&lds[base + boff[n]]);
    __builtin_amdgcn_s_setprio(1);
#pragma unroll
    for (int m = 0; m < 4; ++m)
#pragma unroll
      for (int n = 0; n < 6; ++n)
        acc[m][n] = MFMA(av[m], bv[n], acc[m][n]);
    __builtin_amdgcn_s_setprio(0);
    SB(); BAR();
  }
#undef SS_STAGE

  // ---- wave-local softmax over 77 valid cols
#pragma unroll
  for (int m = 0; m < 4; ++m)
#pragma unroll
    for (int j = 0; j < 4; ++j) {
      float mx = -1e30f;
#pragma unroll
      for (int n = 0; n < 6; ++n)
        if (n * 16 + l15 < 77) mx = fmaxf(mx, acc[m][n][j]);
#pragma unroll
      for (int o = 8; o; o >>= 1) mx = fmaxf(mx, __shfl_xor(mx, o));
      float sum = 0.f;
#pragma unroll
      for (int n = 0; n < 6; ++n) {
        float e = (n * 16 + l15 < 77) ? __expf(acc[m][n][j] - mx) : 0.f;
        acc[m][n][j] = e;
        sum += e;
      }
#pragma unroll
      for (int o = 8; o; o >>= 1) sum += __shfl_xor(sum, o);
      float inv = 1.f / sum;
#pragma unroll
      for (int n = 0; n < 6; ++n) acc[m][n][j] *= inv;
    }

  // ---- per-wave LDS bounce ([64][88] us), coalesced probs store
  __syncthreads();
  ushort* pw = lds + wid * 5632;
#pragma unroll
  for (int m = 0; m < 4; ++m)
#pragma unroll
    for (int n = 0; n < 5; ++n)
#pragma unroll
      for (int j = 0; j < 4; ++j)
        pw[(m * 16 + l4 * 4 + j) * 88 + n * 16 + l15] = f2bf(acc[m][n][j]);

  const uint* pw32 = (const uint*)pw;
  uint* probs32 = (uint*)probs;
  const int head = h0 + wN;
  const long sbase = (long)z * 4096 + s0 + wM * 64;
#pragma unroll 4
  for (int k = 0; k < 40; ++k) {
    int f2 = k * 64 + lane;
    int r = f2 / 40;
    int tp = f2 - r * 40;
    probs32[(sbase + r) * 320 + head * 40 + tp] = pw32[r * 44 + tp];
  }
}

// ---------------- output GEMM: 128x128, BK=32, ~4 blocks/CU ----------------
// C[z][m][n] = sum_k P[z][m][k]*Nt[z][n][k] + bias[n]. M=4096, N=1280, K=640 (20 steps).
// LDS: 2 bufs x (A[128][32] | B[128][32]) = 32 KiB. Counted vmcnt(4).
__global__ __launch_bounds__(256, 2) void gemm_out(
    const ushort* __restrict__ P, const ushort* __restrict__ Nt,
    float* __restrict__ C, const float* __restrict__ bias)
{
  __shared__ ushort lds[16384];

  const int z = blockIdx.z;
  const ushort* Ab = P + (long)z * (4096L * 640) + (long)blockIdx.x * 128 * 640;
  const ushort* Bb = Nt + (long)z * (1280L * 640) + (long)blockIdx.y * 128 * 640;
  const int tid = threadIdx.x;
  const int lane = tid & 63;
  const int wid = tid >> 6;
  const int wM = wid >> 1;   // 0..1
  const int wN = wid & 1;    // 0..1
  const int l15 = lane & 15;
  const int l4 = lane >> 4;
  const int sl = tid & 3;

  long asrc[2]; int adst[2], bdst[2];
#pragma unroll
  for (int j = 0; j < 2; ++j) {
    int r = j * 64 + (tid >> 2);
    asrc[j] = (long)r * 640 + ((sl ^ KEY4(r)) * 8);   // same for A and B
    adst[j] = (j * 256 + tid) * 8;
    bdst[j] = 4096 + (j * 256 + tid) * 8;
  }

  int aoff[4], boff[4];
#pragma unroll
  for (int m = 0; m < 4; ++m) {
    int r = wM * 64 + m * 16 + l15;
    aoff[m] = r * 32 + ((l4 ^ KEY4(r)) * 8);
  }
#pragma unroll
  for (int n = 0; n < 4; ++n) {
    int r = wN * 64 + n * 16 + l15;
    boff[n] = 4096 + r * 32 + ((l4 ^ KEY4(r)) * 8);
  }

  f32x4 acc[4][4] = {};

#define OG_STAGE(bb, kt) { \
    _Pragma("unroll") for (int j = 0; j < 2; ++j) gload16(Ab + asrc[j] + (kt), &lds[(bb) + adst[j]]); \
    _Pragma("unroll") for (int j = 0; j < 2; ++j) gload16(Bb + asrc[j] + (kt), &lds[(bb) + bdst[j]]); }

  OG_STAGE(0, 0)

  for (int t = 0; t < 20; ++t) {
    const int base = (t & 1) * 8192;
    if (t + 1 < 20) {
      OG_STAGE(8192 - base, (t + 1) * 32)
      asm volatile("s_waitcnt vmcnt(4)" ::: "memory");
    } else {
      asm volatile("s_waitcnt vmcnt(0)" ::: "memory");
    }
    SB(); BAR(); SB();
    bf16x8 av[4], bv[4];
#pragma unroll
    for (int m = 0; m < 4; ++m) av[m] = *(const bf16x8*)(&lds[base + aoff[m]]);
#pragma unroll
    for (int n = 0; n < 4; ++n) bv[n] = *(const bf16x8*)(&lds[base + boff[n]]);
    __builtin_amdgcn_s_setprio(1);
#pragma unroll
    for (int m = 0; m < 4; ++m)
#pragma unroll
      for (int n = 0; n < 4; ++n)
        acc[m][n] = MFMA(av[m], bv[n], acc[m][n]);
    __builtin_amdgcn_s_setprio(0);
    SB(); BAR();
  }
#undef OG_STAGE

  // ---- coalesced C write via per-wave LDS bounce ([16][68] f32)
  __syncthreads();
  float* pw = (float*)lds + wid * 1088;
  const int ccol = blockIdx.y * 128 + wN * 64;
  const float4 bv4 = *(const float4*)(bias + ccol + l15 * 4);
  const long crow0 = (long)z * 4096 + blockIdx.x * 128 + wM * 64;
#pragma unroll
  for (int m = 0; m < 4; ++m) {
#pragma unroll
    for (int n = 0; n < 4; ++n)
#pragma unroll
      for (int j = 0; j < 4; ++j)
        pw[(l4 * 4 + j) * 68 + n * 16 + l15] = acc[m][n][j];
    asm volatile("s_waitcnt lgkmcnt(0)" ::: "memory"); SB();
#pragma unroll
    for (int pass = 0; pass < 4; ++pass) {
      int r = pass * 4 + l4;
      float4 v = *(const float4*)(pw + r * 68 + l15 * 4);
      v.x += bv4.x; v.y += bv4.y; v.z += bv4.z; v.w += bv4.w;
      *(float4*)(C + (crow0 + m * 16 + r) * 1280 + ccol + l15 * 4) = v;
    }
    asm volatile("s_waitcnt lgkmcnt(0)" ::: "memory"); SB();
  }
}

extern "C" void kernel_launch(void* const* d_in, const int* in_sizes, int n_in,
                              void* d_out, int out_size, void* d_ws, size_t ws_size,
                              hipStream_t stream) {
  (void)in_sizes; (void)n_in; (void)out_size; (void)ws_size;
  const float* hs     = (const float*)d_in[0];
  const float* ehs    = (const float*)d_in[1];
  const float* Wq     = (const float*)d_in[2];
  const float* Wk     = (const float*)d_in[3];
  const float* Wv     = (const float*)d_in[4];
  const float* Wo     = (const float*)d_in[5];
  const float* bo     = (const float*)d_in[6];
  const float* q_down = (const float*)d_in[7];
  const float* q_up   = (const float*)d_in[8];
  const float* k_down = (const float*)d_in[9];
  const float* k_up   = (const float*)d_in[10];
  const float* v_down = (const float*)d_in[11];
  const float* v_up   = (const float*)d_in[12];
  const float* o_down = (const float*)d_in[13];
  const float* o_up   = (const float*)d_in[14];

  char* w = (char*)d_ws;
  size_t off = 0;
  auto alloc = [&](size_t b) { char* p = w + off; off = (off + b + 255) & ~(size_t)255; return p; };
  ushort* hs_bf  = (ushort*)alloc(32768L * 1280 * 2);
  ushort* ehs_bf = (ushort*)alloc(616L * 768 * 2);
  ushort* WqT    = (ushort*)alloc(1280L * 1280 * 2);   // Wq_eff^T * inv_sqrt(DH)
  ushort* Wkv    = (ushort*)alloc(2560L * 768 * 2);    // [Wk_eff; Wv_eff]
  ushort* Wo_bf  = (ushort*)alloc(1280L * 1280 * 2);
  ushort* kv_bf  = (ushort*)alloc(616L * 2560 * 2);    // k | v
  ushort* Mt     = (ushort*)alloc(8L * 640 * 1280 * 2);
  ushort* Nt     = (ushort*)alloc(8L * 1280 * 640 * 2);  // col = h*80+t
  ushort* probs  = (ushort*)alloc(8L * 4096 * 640 * 2);  // col = h*80+t
  float*  outp   = (float*)d_out;
  const float invs = 0.07905694150420949f;  // 1/sqrt(160)

  // fused prep: cvt_hs + cvt_ehs + 4 folds + Nt pad zeros
  prep_fused<<<42151, 256, 0, stream>>>(hs, hs_bf, ehs, ehs_bf,
      Wq, q_up, q_down, WqT, Wk, k_up, k_down, Wv, v_up, v_down, Wkv,
      Wo, o_up, o_down, Wo_bf, Nt, invs);
  // fused k|v projection: (616x768)@(768->2560), bf16 out
  gemm_bt<<<dim3(5, 20, 1), 256, 0, stream>>>(ehs_bf, 0, 0, 768, 616,
      Wkv, 0, 0, 768, 2560, nullptr, kv_bf, 0, 0, 2560, nullptr, 768);
  // Mt[b][h*77+t][i] = inv_sqrt * sum_d k[b,t,h*160+d] * Wq_eff[h*160+d][i]   (z = b*8+h)
  gemm_bt<<<dim3(1, 10, 64), 256, 0, stream>>>(kv_bf, 77L * 2560, 160, 2560, 77,
      WqT, 0, 160, 1280, 1280, nullptr, Mt, 640L * 1280, 77L * 1280, 1280, nullptr, 160);
  // Nt[b][j][h*80+t] = sum_d Wo_eff[j][h*160+d] * v[b,t,h*160+d]
  gemm_bt<<<dim3(10, 1, 64), 256, 0, stream>>>(Wo_bf, 0, 160, 1280, 1280,
      kv_bf + 1280, 77L * 2560, 160, 2560, 77, nullptr, Nt, 1280L * 640, 80, 640, nullptr, 160);
  // fused scores + softmax -> probs bf16 (col = h*80+t)
  score_softmax<<<dim3(32, 4, 8), 256, 0, stream>>>(hs_bf, Mt, probs);
  // out = probs @ Nt^T + bo
  gemm_out<<<dim3(32, 10, 8), 256, 0, stream>>>(probs, Nt, outp, bo);
}